// Round 5
// baseline (391.909 us; speedup 1.0000x reference)
//
#include <hip/hip_runtime.h>

typedef __attribute__((ext_vector_type(4))) float f32x4;
typedef __attribute__((ext_vector_type(8))) short s16x8;
typedef __attribute__((ext_vector_type(8))) unsigned short u16x8;

#define AS1(p) ((const __attribute__((address_space(1))) void*)(p))
#define AS3(p) ((__attribute__((address_space(3))) void*)(p))

__device__ __forceinline__ unsigned short f2bf(float f) {
  unsigned u = __builtin_bit_cast(unsigned, f);
  u += 0x7fffu + ((u >> 16) & 1u);   // RNE; inputs are finite
  return (unsigned short)(u >> 16);
}
__device__ __forceinline__ float bf2f(unsigned short s) {
  unsigned u = ((unsigned)s) << 16;
  return __builtin_bit_cast(float, u);
}

// ---------------- fp32 -> bf16 cast (vectorized, grid-stride) ----------------
__global__ __launch_bounds__(256) void cast_bf16(const float* __restrict__ in,
                                                 unsigned short* __restrict__ out,
                                                 long n) {
  long i = ((long)blockIdx.x * 256 + threadIdx.x) * 4;
  long stride = (long)gridDim.x * 256 * 4;
  for (; i < n; i += stride) {
    float4 f = *(const float4*)(in + i);
    ushort4 o = { f2bf(f.x), f2bf(f.y), f2bf(f.z), f2bf(f.w) };
    *(ushort4*)(out + i) = o;
  }
}

// ---------------- hierarchical column cummax scan ----------------
__global__ __launch_bounds__(256) void scan_chunkmax(const float* __restrict__ x,
                                                     float* __restrict__ partial) {
  int col = blockIdx.x * 256 + threadIdx.x;
  int chunk = blockIdx.y;
  const float* p = x + (long)chunk * 64 * 1024 + col;
  float m = -INFINITY;
#pragma unroll 4
  for (int i = 0; i < 64; i++) m = fmaxf(m, p[(long)i * 1024]);
  partial[chunk * 1024 + col] = m;
}

__global__ __launch_bounds__(256) void scan_chunkscan(const float* __restrict__ partial,
                                                      float* __restrict__ prefix,
                                                      float* __restrict__ suffix) {
  int col = blockIdx.x * 256 + threadIdx.x;
  float run = -INFINITY;
  for (int c = 0; c < 128; c++) {
    prefix[c * 1024 + col] = run;
    run = fmaxf(run, partial[c * 1024 + col]);
  }
  run = -INFINITY;
  for (int c = 127; c >= 0; c--) {
    suffix[c * 1024 + col] = run;
    run = fmaxf(run, partial[c * 1024 + col]);
  }
}

__global__ __launch_bounds__(256) void scan_emit(const float* __restrict__ x,
                                                 const float* __restrict__ prefix,
                                                 const float* __restrict__ suffix,
                                                 unsigned short* __restrict__ h_in) {
  int col = blockIdx.x * 256 + threadIdx.x;
  int chunk = blockIdx.y;
  long r0 = (long)chunk * 64;
  float run = prefix[chunk * 1024 + col];
  for (int i = 0; i < 64; i++) {
    long row = r0 + i;
    float v = x[row * 1024 + col];
    unsigned short* hr = h_in + row * 3072;
    hr[col] = f2bf(v);
    hr[1024 + col] = f2bf(row == 0 ? 0.f : run);
    run = fmaxf(run, v);
  }
  float run2 = suffix[chunk * 1024 + col];
  for (int i = 63; i >= 0; i--) {
    long row = r0 + i;
    float v = x[row * 1024 + col];
    h_in[row * 3072 + 2048 + col] = f2bf(row == 8191 ? 0.f : run2);
    run2 = fmaxf(run2, v);
  }
}

// ============ 256x256 8-phase bf16 GEMM: C = relu(A@B^T + bias) ============
// A [M,K], B [N,K] bf16 row-major. 512 thr = 8 waves (2M x 4N), per-wave out 128x64.
// BK=64, counted vmcnt, setprio MFMA clusters.
// LDS swizzle (r4, conflict-free verified: SQ_LDS_BANK_CONFLICT=0): byte ^= (row&7)<<4,
//   applied as linear LDS dest + inverse-swizzled GLOBAL source + swizzled ds_read.
// r5: A-prefetch deepened to 2 tiles ahead (was 1; ~450cy slack < ~900cy HBM latency
//   was the vmcnt stall). A triple-buffered 3x32KB @0/32K/64K, B double 2x32KB
//   @96K/128K = 160KB LDS. vmcnt(8) at group start drains tile g+1 exactly,
//   leaves tile g+2's 8 loads in flight. Clobber-safe: A(g+2)->region (g+2)%3,
//   last read as tile g-1 in group g-1, complete at that group's final barrier,
//   before this stage issues. B unchanged (reads all at q0; restage q1/q2).
__global__ __launch_bounds__(512, 2) void gemm256_relu(
    const unsigned short* __restrict__ A, const unsigned short* __restrict__ B,
    unsigned short* __restrict__ C, const float* __restrict__ bias,
    int M, int N, int K) {
  extern __shared__ char smem[];  // A: 3x32K | B: 2x32K = 163840 B
  const int NT = K >> 6;          // K-tiles of 64

  // XCD-chunked swizzle (grid %8 == 0)
  const int nwg = gridDim.x;
  const int cpx = nwg >> 3;
  const int bid = blockIdx.x;
  const int swz = (bid & 7) * cpx + (bid >> 3);
  const int tiles_m = M >> 8;
  const int tm = swz % tiles_m;
  const int tn = swz / tiles_m;
  const long brow = (long)tm * 256;
  const long bcol = (long)tn * 256;

  const int t = threadIdx.x;
  const int lane = t & 63, wv = t >> 6;
  const int wr = wv >> 2, wc = wv & 3;
  const int fr = lane & 15, fk = lane >> 4;

  // staging: thread t -> linear LDS byte t*16 in region; row=t>>3, phys col=(t&7)*16;
  // inverse swizzle: scol elems = 8*((t&7) ^ ((t>>3)&7)).
  const int srow = t >> 3;
  const int scol = 8 * ((t & 7) ^ ((t >> 3) & 7));
  const unsigned short* Asrc = A + (brow + srow) * (long)K + scol;
  const unsigned short* Bsrc = B + (bcol + srow) * (long)K + scol;
  const long hstep = (long)128 * K, lstep = (long)64 * K;

#define STAGE_A(j, reg, h, L)                                                  \
  __builtin_amdgcn_global_load_lds(AS1(Asrc + (h)*hstep + (L)*lstep + (j)*64), \
      AS3(smem + (reg)*32768 + (h)*16384 + (L)*8192 + t * 16), 16, 0, 0)
#define STAGE_B(j, h, L)                                                       \
  __builtin_amdgcn_global_load_lds(AS1(Bsrc + (h)*hstep + (L)*lstep + (j)*64), \
      AS3(smem + 98304 + ((j)&1) * 32768 + (h)*16384 + (L)*8192 + t * 16), 16, 0, 0)

  // ds_read: logical byte = row*128 + kk*64 + fk*16; physical ^= (row&7)<<4;
  // row&7 = fr&7 (all other row terms have zero low-3 bits).
  const int xr = (fr & 7) << 4;
  const char* ArdRow = smem + (wr * 128 + fr) * 128;
  const char* BrdRow = smem + 98304 + (wc * 64 + fr) * 128;
#define RD_A(ar_, m, kk) \
  (*(const s16x8*)(ArdRow + (ar_)*32768 + (m)*2048 + (((kk)*64 + fk * 16) ^ xr)))
#define RD_B(pb_, n, kk) \
  (*(const s16x8*)(BrdRow + (pb_)*32768 + (n)*2048 + (((kk)*64 + fk * 16) ^ xr)))

  f32x4 acc[8][4];
#pragma unroll
  for (int m = 0; m < 8; m++)
#pragma unroll
    for (int n = 0; n < 4; n++) acc[m][n] = (f32x4)0.f;

  // prologue (issue order matters for vmcnt drain): A0, B0, A1, B1 = 16 loads
  STAGE_A(0, 0, 0, 0); STAGE_A(0, 0, 0, 1); STAGE_A(0, 0, 1, 0); STAGE_A(0, 0, 1, 1);
  STAGE_B(0, 0, 0); STAGE_B(0, 0, 1); STAGE_B(0, 1, 0); STAGE_B(0, 1, 1);
  STAGE_A(1, 1, 0, 0); STAGE_A(1, 1, 0, 1); STAGE_A(1, 1, 1, 0); STAGE_A(1, 1, 1, 1);
  STAGE_B(1, 0, 0); STAGE_B(1, 0, 1); STAGE_B(1, 1, 0); STAGE_B(1, 1, 1);

  int ar = 0;  // g % 3
  for (int g = 0; g < NT; ++g) {
    const int pb = g & 1;
    int sr = ar + 2; if (sr >= 3) sr -= 3;  // (g+2) % 3
    if (g + 1 < NT) asm volatile("s_waitcnt vmcnt(8)" ::: "memory");
    else            asm volatile("s_waitcnt vmcnt(0)" ::: "memory");
    __builtin_amdgcn_s_barrier();
    s16x8 bfr[4][2];
#pragma unroll
    for (int q = 0; q < 4; ++q) {
      if (q == 0) {
#pragma unroll
        for (int n = 0; n < 4; ++n) {
          bfr[n][0] = RD_B(pb, n, 0);
          bfr[n][1] = RD_B(pb, n, 1);
        }
      }
      s16x8 afr[2][2];
#pragma unroll
      for (int i = 0; i < 2; ++i) {
        afr[i][0] = RD_A(ar, 2 * q + i, 0);
        afr[i][1] = RD_A(ar, 2 * q + i, 1);
      }
      if (q == 0 && g + 2 < NT) {
        STAGE_A(g + 2, sr, 0, 0); STAGE_A(g + 2, sr, 0, 1);
        STAGE_A(g + 2, sr, 1, 0); STAGE_A(g + 2, sr, 1, 1);
      }
      if (q == 1 && g + 2 < NT) { STAGE_B(g + 2, 0, 0); STAGE_B(g + 2, 0, 1); }
      if (q == 2 && g + 2 < NT) { STAGE_B(g + 2, 1, 0); STAGE_B(g + 2, 1, 1); }
      __builtin_amdgcn_s_barrier();
      asm volatile("s_waitcnt lgkmcnt(0)" ::: "memory");
      __builtin_amdgcn_s_setprio(1);
#pragma unroll
      for (int i = 0; i < 2; ++i)
#pragma unroll
        for (int n = 0; n < 4; ++n) {
          acc[2 * q + i][n] = __builtin_amdgcn_mfma_f32_16x16x32_bf16(
              afr[i][0], bfr[n][0], acc[2 * q + i][n], 0, 0, 0);
          acc[2 * q + i][n] = __builtin_amdgcn_mfma_f32_16x16x32_bf16(
              afr[i][1], bfr[n][1], acc[2 * q + i][n], 0, 0, 0);
        }
      __builtin_amdgcn_s_setprio(0);
      __builtin_amdgcn_s_barrier();
    }
    ar = (ar == 2) ? 0 : ar + 1;
  }

  // epilogue: C/D layout col=lane&15, row=(lane>>4)*4+reg
  float bi[4];
#pragma unroll
  for (int n = 0; n < 4; ++n) bi[n] = bias[bcol + wc * 64 + n * 16 + fr];
  const long orow = brow + wr * 128 + fk * 4;
  const long ocol = bcol + wc * 64 + fr;
#pragma unroll
  for (int m = 0; m < 8; ++m)
#pragma unroll
    for (int n = 0; n < 4; ++n)
#pragma unroll
      for (int r = 0; r < 4; ++r) {
        float v = acc[m][n][r] + bi[n];
        v = v > 0.f ? v : 0.f;
        C[(orow + m * 16 + r) * (long)N + ocol + n * 16] = f2bf(v);
      }
#undef STAGE_A
#undef STAGE_B
#undef RD_A
#undef RD_B
}

// ---------------- m97-structure 128^2 bf16 GEMM (N=1024 GEMM2) ----------------
// LDS rows are 64 B: byte ^= ((row>>1)&3)<<4; source pre-swizzled to match.
__global__ __launch_bounds__(256) void gemm_bt2(const unsigned short* __restrict__ A,
                                                const unsigned short* __restrict__ B,
                                                float* __restrict__ Cf,
                                                const float* __restrict__ bias,
                                                const float* __restrict__ gamma,
                                                const float* __restrict__ resid,
                                                int M, int N, int K) {
  constexpr int BK = 32;
  __shared__ unsigned short As[128 * BK];
  __shared__ unsigned short Bs[128 * BK];
  const int tid = threadIdx.x;
  const int lane = tid & 63;
  const int wave = tid >> 6;
  const int wr = wave >> 1, wc = wave & 1;
  const long brow = (long)blockIdx.y * 128;
  const long bcol = (long)blockIdx.x * 128;

  const int scol = ((tid & 3) * 8) ^ ((((tid >> 3) & 3)) << 3);
  const unsigned short* Ag = A + (brow + (tid >> 2)) * (long)K + scol;
  const unsigned short* Bg = B + (bcol + (tid >> 2)) * (long)K + scol;
  const long rstep = (long)64 * K;

  f32x4 acc[4][4];
#pragma unroll
  for (int m = 0; m < 4; m++)
#pragma unroll
    for (int n = 0; n < 4; n++) acc[m][n] = (f32x4)0.f;

  const int fr = lane & 15, fk = lane >> 4;
  const int xr2 = ((fr >> 1) & 3) << 4;
  const char* Ard = (const char*)As + (wr * 64 + fr) * 64;
  const char* Brd = (const char*)Bs + (wc * 64 + fr) * 64;
#define RD2_A(m) (*(const s16x8*)(Ard + (m)*1024 + (fk * 16 ^ xr2)))
#define RD2_B(n) (*(const s16x8*)(Brd + (n)*1024 + (fk * 16 ^ xr2)))

  for (int k0 = 0; k0 < K; k0 += BK) {
    __syncthreads();
    __builtin_amdgcn_global_load_lds(AS1(Ag + k0), AS3((char*)As + tid * 16), 16, 0, 0);
    __builtin_amdgcn_global_load_lds(AS1(Ag + k0 + rstep), AS3((char*)As + 4096 + tid * 16), 16, 0, 0);
    __builtin_amdgcn_global_load_lds(AS1(Bg + k0), AS3((char*)Bs + tid * 16), 16, 0, 0);
    __builtin_amdgcn_global_load_lds(AS1(Bg + k0 + rstep), AS3((char*)Bs + 4096 + tid * 16), 16, 0, 0);
    __syncthreads();
    s16x8 af[4], bg[4];
#pragma unroll
    for (int m = 0; m < 4; m++) af[m] = RD2_A(m);
#pragma unroll
    for (int n = 0; n < 4; n++) bg[n] = RD2_B(n);
#pragma unroll
    for (int m = 0; m < 4; m++)
#pragma unroll
      for (int n = 0; n < 4; n++)
        acc[m][n] = __builtin_amdgcn_mfma_f32_16x16x32_bf16(af[m], bg[n], acc[m][n], 0, 0, 0);
  }
#undef RD2_A
#undef RD2_B

  const long orow = brow + wr * 64 + fk * 4;
  const long ocol = bcol + wc * 64 + fr;
#pragma unroll
  for (int m = 0; m < 4; m++) {
#pragma unroll
    for (int n = 0; n < 4; n++) {
      const long col = ocol + n * 16;
      const float bi = bias[col];
      const float ga = gamma[col];
#pragma unroll
      for (int r = 0; r < 4; r++) {
        const long row = orow + m * 16 + r;
        Cf[row * N + col] = (acc[m][n][r] + bi) * ga + resid[row * N + col];
      }
    }
  }
}

// ---------------- in-place LayerNorm over D=4096, one block per row ----------------
__global__ __launch_bounds__(256) void ln_inplace(unsigned short* __restrict__ h,
                                                  const float* __restrict__ w,
                                                  const float* __restrict__ b) {
  unsigned short* hp = h + (long)blockIdx.x * 4096;
  const int tid = threadIdx.x;
  u16x8 a0 = ((const u16x8*)hp)[tid * 2];
  u16x8 a1 = ((const u16x8*)hp)[tid * 2 + 1];
  float v[16];
#pragma unroll
  for (int j = 0; j < 8; j++) { v[j] = bf2f(a0[j]); v[8 + j] = bf2f(a1[j]); }
  float s = 0.f, q = 0.f;
#pragma unroll
  for (int j = 0; j < 16; j++) { s += v[j]; q += v[j] * v[j]; }
#pragma unroll
  for (int off = 32; off; off >>= 1) {
    s += __shfl_xor(s, off, 64);
    q += __shfl_xor(q, off, 64);
  }
  __shared__ float ss[4], sq[4];
  const int wv = tid >> 6;
  if ((tid & 63) == 0) { ss[wv] = s; sq[wv] = q; }
  __syncthreads();
  s = ss[0] + ss[1] + ss[2] + ss[3];
  q = sq[0] + sq[1] + sq[2] + sq[3];
  const float mu = s * (1.f / 4096.f);
  const float var = q * (1.f / 4096.f) - mu * mu;
  const float rs = rsqrtf(var + 1e-6f);
  u16x8 o0, o1;
#pragma unroll
  for (int j = 0; j < 8; j++) {
    int c0 = tid * 16 + j, c1 = c0 + 8;
    o0[j] = f2bf((v[j] - mu) * rs * w[c0] + b[c0]);
    o1[j] = f2bf((v[8 + j] - mu) * rs * w[c1] + b[c1]);
  }
  ((u16x8*)hp)[tid * 2] = o0;
  ((u16x8*)hp)[tid * 2 + 1] = o1;
}

extern "C" void kernel_launch(void* const* d_in, const int* in_sizes, int n_in,
                              void* d_out, int out_size, void* d_ws, size_t ws_size,
                              hipStream_t stream) {
  const float* x     = (const float*)d_in[0];
  const float* W1    = (const float*)d_in[1];
  const float* b1    = (const float*)d_in[2];
  const float* ln_w  = (const float*)d_in[3];
  const float* ln_b  = (const float*)d_in[4];
  const float* W2    = (const float*)d_in[5];
  const float* b2    = (const float*)d_in[6];
  const float* gamma = (const float*)d_in[7];
  float* out = (float*)d_out;

  const int Nr = 8192, DIM = 1024, DFF = 4096, K1 = 3072;

  unsigned short* W1b  = (unsigned short*)d_ws;
  unsigned short* W2b  = W1b + (long)DFF * K1;
  unsigned short* h_in = W2b + (long)DIM * DFF;
  unsigned short* h_act = h_in + (long)Nr * K1;
  float* partial = (float*)(h_act + (long)Nr * DFF);
  float* prefix  = partial + 128 * 1024;
  float* suffix  = prefix + 128 * 1024;

  hipFuncSetAttribute((const void*)gemm256_relu,
                      hipFuncAttributeMaxDynamicSharedMemorySize, 163840);

  cast_bf16<<<2048, 256, 0, stream>>>(W1, W1b, (long)DFF * K1);
  cast_bf16<<<1024, 256, 0, stream>>>(W2, W2b, (long)DIM * DFF);

  scan_chunkmax<<<dim3(4, 128), 256, 0, stream>>>(x, partial);
  scan_chunkscan<<<4, 256, 0, stream>>>(partial, prefix, suffix);
  scan_emit<<<dim3(4, 128), 256, 0, stream>>>(x, prefix, suffix, h_in);

  // GEMM1: h_act = relu(h_in @ W1^T + b1)  — 256^2 8-phase, grid 32x16=512
  gemm256_relu<<<512, 512, 163840, stream>>>(h_in, W1b, h_act, b1, Nr, DFF, K1);

  ln_inplace<<<Nr, 256, 0, stream>>>(h_act, ln_w, ln_b);

  // GEMM2: out = (h_act @ W2^T + b2) * gamma + x  — m97 128^2
  gemm_bt2<<<dim3(DIM / 128, Nr / 128), 256, 0, stream>>>(
      h_act, W2b, out, b2, gamma, x, Nr, DIM, DFF);
}

// Round 6
// 385.275 us; speedup vs baseline: 1.0172x; 1.0172x over previous
//
#include <hip/hip_runtime.h>

typedef __attribute__((ext_vector_type(4))) float f32x4;
typedef __attribute__((ext_vector_type(8))) short s16x8;
typedef __attribute__((ext_vector_type(8))) unsigned short u16x8;

#define AS1(p) ((const __attribute__((address_space(1))) void*)(p))
#define AS3(p) ((__attribute__((address_space(3))) void*)(p))

__device__ __forceinline__ unsigned short f2bf(float f) {
  unsigned u = __builtin_bit_cast(unsigned, f);
  u += 0x7fffu + ((u >> 16) & 1u);   // RNE; inputs are finite
  return (unsigned short)(u >> 16);
}
__device__ __forceinline__ float bf2f(unsigned short s) {
  unsigned u = ((unsigned)s) << 16;
  return __builtin_bit_cast(float, u);
}

// ---------------- fp32 -> bf16 cast (vectorized, grid-stride) ----------------
__global__ __launch_bounds__(256) void cast_bf16(const float* __restrict__ in,
                                                 unsigned short* __restrict__ out,
                                                 long n) {
  long i = ((long)blockIdx.x * 256 + threadIdx.x) * 4;
  long stride = (long)gridDim.x * 256 * 4;
  for (; i < n; i += stride) {
    float4 f = *(const float4*)(in + i);
    ushort4 o = { f2bf(f.x), f2bf(f.y), f2bf(f.z), f2bf(f.w) };
    *(ushort4*)(out + i) = o;
  }
}

// ---------------- hierarchical column cummax scan ----------------
__global__ __launch_bounds__(256) void scan_chunkmax(const float* __restrict__ x,
                                                     float* __restrict__ partial) {
  int col = blockIdx.x * 256 + threadIdx.x;
  int chunk = blockIdx.y;
  const float* p = x + (long)chunk * 64 * 1024 + col;
  float m = -INFINITY;
#pragma unroll 4
  for (int i = 0; i < 64; i++) m = fmaxf(m, p[(long)i * 1024]);
  partial[chunk * 1024 + col] = m;
}

__global__ __launch_bounds__(256) void scan_chunkscan(const float* __restrict__ partial,
                                                      float* __restrict__ prefix,
                                                      float* __restrict__ suffix) {
  int col = blockIdx.x * 256 + threadIdx.x;
  float run = -INFINITY;
  for (int c = 0; c < 128; c++) {
    prefix[c * 1024 + col] = run;
    run = fmaxf(run, partial[c * 1024 + col]);
  }
  run = -INFINITY;
  for (int c = 127; c >= 0; c--) {
    suffix[c * 1024 + col] = run;
    run = fmaxf(run, partial[c * 1024 + col]);
  }
}

__global__ __launch_bounds__(256) void scan_emit(const float* __restrict__ x,
                                                 const float* __restrict__ prefix,
                                                 const float* __restrict__ suffix,
                                                 unsigned short* __restrict__ h_in) {
  int col = blockIdx.x * 256 + threadIdx.x;
  int chunk = blockIdx.y;
  long r0 = (long)chunk * 64;
  float run = prefix[chunk * 1024 + col];
  for (int i = 0; i < 64; i++) {
    long row = r0 + i;
    float v = x[row * 1024 + col];
    unsigned short* hr = h_in + row * 3072;
    hr[col] = f2bf(v);
    hr[1024 + col] = f2bf(row == 0 ? 0.f : run);
    run = fmaxf(run, v);
  }
  float run2 = suffix[chunk * 1024 + col];
  for (int i = 63; i >= 0; i--) {
    long row = r0 + i;
    float v = x[row * 1024 + col];
    h_in[row * 3072 + 2048 + col] = f2bf(row == 8191 ? 0.f : run2);
    run2 = fmaxf(run2, v);
  }
}

// ============ 256x256 bf16 GEMM, pipelined group schedule: C = relu(A@B^T + bias) ============
// A [M,K], B [N,K] bf16 row-major. 512 thr = 8 waves (2M x 4N), per-wave out 128x64.
// BK=64. LDS: A 3x32K @0/32/64K (2-ahead prefetch), B 2x32K @96/128K = 160 KB.
// Swizzle (r4, verified conflict-free): byte ^= (row&7)<<4; linear LDS dest +
//   inverse-swizzled global source + swizzled ds_read.
// r6 schedule (2 barriers/group; reads pipelined under MFMA):
//   [1] barrier (vmcnt'd tile g published)
//   read B x8, A0 x4, A1 x4      <- one burst; A1 flies under q0's MFMA
//   MFMA q0 (m0,1)               <- compiler-counted lgkm wait
//   lgkmcnt(0); sched_barrier; [2] barrier   <- all waves' reads retired
//   stage A(g+2) x4, B(g+2) x4   <- B restage safe after [2]; A region (g+2)%3 free
//   read A2 ; MFMA q1 ; read A3 ; MFMA q2 ; MFMA q3   <- reads hidden under MFMA
//   vmcnt(8) [tail: vmcnt(0)]    <- drains tile g+1, leaves g+2 in flight
__global__ __launch_bounds__(512, 2) void gemm256_relu(
    const unsigned short* __restrict__ A, const unsigned short* __restrict__ B,
    unsigned short* __restrict__ C, const float* __restrict__ bias,
    int M, int N, int K) {
  extern __shared__ char smem[];
  const int NT = K >> 6;

  // XCD-chunked swizzle (grid %8 == 0)
  const int nwg = gridDim.x;
  const int cpx = nwg >> 3;
  const int bid = blockIdx.x;
  const int swz = (bid & 7) * cpx + (bid >> 3);
  const int tiles_m = M >> 8;
  const int tm = swz % tiles_m;
  const int tn = swz / tiles_m;
  const long brow = (long)tm * 256;
  const long bcol = (long)tn * 256;

  const int t = threadIdx.x;
  const int lane = t & 63, wv = t >> 6;
  const int wr = wv >> 2, wc = wv & 3;
  const int fr = lane & 15, fk = lane >> 4;

  const int srow = t >> 3;
  const int scol = 8 * ((t & 7) ^ ((t >> 3) & 7));
  const unsigned short* Asrc = A + (brow + srow) * (long)K + scol;
  const unsigned short* Bsrc = B + (bcol + srow) * (long)K + scol;
  const long hstep = (long)128 * K, lstep = (long)64 * K;

#define STAGE_A(j, reg, h, L)                                                  \
  __builtin_amdgcn_global_load_lds(AS1(Asrc + (h)*hstep + (L)*lstep + (j)*64), \
      AS3(smem + (reg)*32768 + (h)*16384 + (L)*8192 + t * 16), 16, 0, 0)
#define STAGE_B(j, h, L)                                                       \
  __builtin_amdgcn_global_load_lds(AS1(Bsrc + (h)*hstep + (L)*lstep + (j)*64), \
      AS3(smem + 98304 + ((j)&1) * 32768 + (h)*16384 + (L)*8192 + t * 16), 16, 0, 0)

  const int xr = (fr & 7) << 4;
  const char* ArdRow = smem + (wr * 128 + fr) * 128;
  const char* BrdRow = smem + 98304 + (wc * 64 + fr) * 128;
#define RD_A(ar_, m, kk) \
  (*(const s16x8*)(ArdRow + (ar_)*32768 + (m)*2048 + (((kk)*64 + fk * 16) ^ xr)))
#define RD_B(pb_, n, kk) \
  (*(const s16x8*)(BrdRow + (pb_)*32768 + (n)*2048 + (((kk)*64 + fk * 16) ^ xr)))

#define MFMA_PAIR(mi, a_)                                                      \
  _Pragma("unroll")                                                            \
  for (int n = 0; n < 4; ++n) {                                                \
    acc[(mi)][n] = __builtin_amdgcn_mfma_f32_16x16x32_bf16(                    \
        a_[0], bfr[n][0], acc[(mi)][n], 0, 0, 0);                              \
    acc[(mi)][n] = __builtin_amdgcn_mfma_f32_16x16x32_bf16(                    \
        a_[1], bfr[n][1], acc[(mi)][n], 0, 0, 0);                              \
  }

  f32x4 acc[8][4];
#pragma unroll
  for (int m = 0; m < 8; m++)
#pragma unroll
    for (int n = 0; n < 4; n++) acc[m][n] = (f32x4)0.f;

  // prologue: tile0 (A,B), tile1 (A,B) = 16 loads; drain tile0 before loop
  STAGE_A(0, 0, 0, 0); STAGE_A(0, 0, 0, 1); STAGE_A(0, 0, 1, 0); STAGE_A(0, 0, 1, 1);
  STAGE_B(0, 0, 0); STAGE_B(0, 0, 1); STAGE_B(0, 1, 0); STAGE_B(0, 1, 1);
  STAGE_A(1, 1, 0, 0); STAGE_A(1, 1, 0, 1); STAGE_A(1, 1, 1, 0); STAGE_A(1, 1, 1, 1);
  STAGE_B(1, 0, 0); STAGE_B(1, 0, 1); STAGE_B(1, 1, 0); STAGE_B(1, 1, 1);
  asm volatile("s_waitcnt vmcnt(8)" ::: "memory");

  int ar = 0;  // g % 3
  for (int g = 0; g < NT; ++g) {
    const int pb = g & 1;
    int sr = ar + 2; if (sr >= 3) sr -= 3;  // (g+2) % 3

    asm volatile("s_barrier" ::: "memory");  // [1] tile g published to all waves

    s16x8 bfr[4][2];
#pragma unroll
    for (int n = 0; n < 4; ++n) {
      bfr[n][0] = RD_B(pb, n, 0);
      bfr[n][1] = RD_B(pb, n, 1);
    }
    s16x8 a0[2], a1[2], a2[2], a3[2];
    a0[0] = RD_A(ar, 0, 0); a0[1] = RD_A(ar, 0, 1);
    a1[0] = RD_A(ar, 1, 0); a1[1] = RD_A(ar, 1, 1);
    s16x8 b0[2], b1[2];
    b0[0] = RD_A(ar, 2, 0); b0[1] = RD_A(ar, 2, 1);
    b1[0] = RD_A(ar, 3, 0); b1[1] = RD_A(ar, 3, 1);

    // q0: m0,m1 (B + A0/A1 reads retire via data-dep; A2-pair reads in flight)
    __builtin_amdgcn_s_setprio(1);
    MFMA_PAIR(0, a0)
    MFMA_PAIR(1, a1)
    __builtin_amdgcn_s_setprio(0);

    asm volatile("s_waitcnt lgkmcnt(0)" ::: "memory");
    __builtin_amdgcn_sched_barrier(0);
    asm volatile("s_barrier" ::: "memory");  // [2] all reads of tile g retired

    if (g + 2 < NT) {
      STAGE_A(g + 2, sr, 0, 0); STAGE_A(g + 2, sr, 0, 1);
      STAGE_A(g + 2, sr, 1, 0); STAGE_A(g + 2, sr, 1, 1);
      STAGE_B(g + 2, 0, 0); STAGE_B(g + 2, 0, 1);
      STAGE_B(g + 2, 1, 0); STAGE_B(g + 2, 1, 1);
    }

    // q1: m2,m3 (already read); prefetch m4,m5
    a2[0] = RD_A(ar, 4, 0); a2[1] = RD_A(ar, 4, 1);
    a3[0] = RD_A(ar, 5, 0); a3[1] = RD_A(ar, 5, 1);
    __builtin_amdgcn_s_setprio(1);
    MFMA_PAIR(2, b0)
    MFMA_PAIR(3, b1)
    __builtin_amdgcn_s_setprio(0);

    // q2: m4,m5; prefetch m6,m7
    s16x8 c0[2], c1[2];
    c0[0] = RD_A(ar, 6, 0); c0[1] = RD_A(ar, 6, 1);
    c1[0] = RD_A(ar, 7, 0); c1[1] = RD_A(ar, 7, 1);
    __builtin_amdgcn_s_setprio(1);
    MFMA_PAIR(4, a2)
    MFMA_PAIR(5, a3)
    // q3: m6,m7
    MFMA_PAIR(6, c0)
    MFMA_PAIR(7, c1)
    __builtin_amdgcn_s_setprio(0);

    if (g + 1 < NT) {
      if (g + 2 < NT) asm volatile("s_waitcnt vmcnt(8)" ::: "memory");
      else            asm volatile("s_waitcnt vmcnt(0)" ::: "memory");
    }
    ar = (ar == 2) ? 0 : ar + 1;
  }

  // epilogue: C/D layout col=lane&15, row=(lane>>4)*4+reg
  float bi[4];
#pragma unroll
  for (int n = 0; n < 4; ++n) bi[n] = bias[bcol + wc * 64 + n * 16 + fr];
  const long orow = brow + wr * 128 + fk * 4;
  const long ocol = bcol + wc * 64 + fr;
#pragma unroll
  for (int m = 0; m < 8; ++m)
#pragma unroll
    for (int n = 0; n < 4; ++n)
#pragma unroll
      for (int r = 0; r < 4; ++r) {
        float v = acc[m][n][r] + bi[n];
        v = v > 0.f ? v : 0.f;
        C[(orow + m * 16 + r) * (long)N + ocol + n * 16] = f2bf(v);
      }
#undef STAGE_A
#undef STAGE_B
#undef RD_A
#undef RD_B
#undef MFMA_PAIR
}

// ---------------- m97-structure 128^2 bf16 GEMM (N=1024 GEMM2) ----------------
// LDS rows are 64 B: byte ^= ((row>>1)&3)<<4; source pre-swizzled to match.
__global__ __launch_bounds__(256) void gemm_bt2(const unsigned short* __restrict__ A,
                                                const unsigned short* __restrict__ B,
                                                float* __restrict__ Cf,
                                                const float* __restrict__ bias,
                                                const float* __restrict__ gamma,
                                                const float* __restrict__ resid,
                                                int M, int N, int K) {
  constexpr int BK = 32;
  __shared__ unsigned short As[128 * BK];
  __shared__ unsigned short Bs[128 * BK];
  const int tid = threadIdx.x;
  const int lane = tid & 63;
  const int wave = tid >> 6;
  const int wr = wave >> 1, wc = wave & 1;
  const long brow = (long)blockIdx.y * 128;
  const long bcol = (long)blockIdx.x * 128;

  const int scol = ((tid & 3) * 8) ^ ((((tid >> 3) & 3)) << 3);
  const unsigned short* Ag = A + (brow + (tid >> 2)) * (long)K + scol;
  const unsigned short* Bg = B + (bcol + (tid >> 2)) * (long)K + scol;
  const long rstep = (long)64 * K;

  f32x4 acc[4][4];
#pragma unroll
  for (int m = 0; m < 4; m++)
#pragma unroll
    for (int n = 0; n < 4; n++) acc[m][n] = (f32x4)0.f;

  const int fr = lane & 15, fk = lane >> 4;
  const int xr2 = ((fr >> 1) & 3) << 4;
  const char* Ard = (const char*)As + (wr * 64 + fr) * 64;
  const char* Brd = (const char*)Bs + (wc * 64 + fr) * 64;
#define RD2_A(m) (*(const s16x8*)(Ard + (m)*1024 + (fk * 16 ^ xr2)))
#define RD2_B(n) (*(const s16x8*)(Brd + (n)*1024 + (fk * 16 ^ xr2)))

  for (int k0 = 0; k0 < K; k0 += BK) {
    __syncthreads();
    __builtin_amdgcn_global_load_lds(AS1(Ag + k0), AS3((char*)As + tid * 16), 16, 0, 0);
    __builtin_amdgcn_global_load_lds(AS1(Ag + k0 + rstep), AS3((char*)As + 4096 + tid * 16), 16, 0, 0);
    __builtin_amdgcn_global_load_lds(AS1(Bg + k0), AS3((char*)Bs + tid * 16), 16, 0, 0);
    __builtin_amdgcn_global_load_lds(AS1(Bg + k0 + rstep), AS3((char*)Bs + 4096 + tid * 16), 16, 0, 0);
    __syncthreads();
    s16x8 af[4], bg[4];
#pragma unroll
    for (int m = 0; m < 4; m++) af[m] = RD2_A(m);
#pragma unroll
    for (int n = 0; n < 4; n++) bg[n] = RD2_B(n);
#pragma unroll
    for (int m = 0; m < 4; m++)
#pragma unroll
      for (int n = 0; n < 4; n++)
        acc[m][n] = __builtin_amdgcn_mfma_f32_16x16x32_bf16(af[m], bg[n], acc[m][n], 0, 0, 0);
  }
#undef RD2_A
#undef RD2_B

  const long orow = brow + wr * 64 + fk * 4;
  const long ocol = bcol + wc * 64 + fr;
#pragma unroll
  for (int m = 0; m < 4; m++) {
#pragma unroll
    for (int n = 0; n < 4; n++) {
      const long col = ocol + n * 16;
      const float bi = bias[col];
      const float ga = gamma[col];
#pragma unroll
      for (int r = 0; r < 4; r++) {
        const long row = orow + m * 16 + r;
        Cf[row * N + col] = (acc[m][n][r] + bi) * ga + resid[row * N + col];
      }
    }
  }
}

// ---------------- in-place LayerNorm over D=4096, one block per row ----------------
__global__ __launch_bounds__(256) void ln_inplace(unsigned short* __restrict__ h,
                                                  const float* __restrict__ w,
                                                  const float* __restrict__ b) {
  unsigned short* hp = h + (long)blockIdx.x * 4096;
  const int tid = threadIdx.x;
  u16x8 a0 = ((const u16x8*)hp)[tid * 2];
  u16x8 a1 = ((const u16x8*)hp)[tid * 2 + 1];
  float v[16];
#pragma unroll
  for (int j = 0; j < 8; j++) { v[j] = bf2f(a0[j]); v[8 + j] = bf2f(a1[j]); }
  float s = 0.f, q = 0.f;
#pragma unroll
  for (int j = 0; j < 16; j++) { s += v[j]; q += v[j] * v[j]; }
#pragma unroll
  for (int off = 32; off; off >>= 1) {
    s += __shfl_xor(s, off, 64);
    q += __shfl_xor(q, off, 64);
  }
  __shared__ float ss[4], sq[4];
  const int wv = tid >> 6;
  if ((tid & 63) == 0) { ss[wv] = s; sq[wv] = q; }
  __syncthreads();
  s = ss[0] + ss[1] + ss[2] + ss[3];
  q = sq[0] + sq[1] + sq[2] + sq[3];
  const float mu = s * (1.f / 4096.f);
  const float var = q * (1.f / 4096.f) - mu * mu;
  const float rs = rsqrtf(var + 1e-6f);
  u16x8 o0, o1;
#pragma unroll
  for (int j = 0; j < 8; j++) {
    int c0 = tid * 16 + j, c1 = c0 + 8;
    o0[j] = f2bf((v[j] - mu) * rs * w[c0] + b[c0]);
    o1[j] = f2bf((v[8 + j] - mu) * rs * w[c1] + b[c1]);
  }
  ((u16x8*)hp)[tid * 2] = o0;
  ((u16x8*)hp)[tid * 2 + 1] = o1;
}

extern "C" void kernel_launch(void* const* d_in, const int* in_sizes, int n_in,
                              void* d_out, int out_size, void* d_ws, size_t ws_size,
                              hipStream_t stream) {
  const float* x     = (const float*)d_in[0];
  const float* W1    = (const float*)d_in[1];
  const float* b1    = (const float*)d_in[2];
  const float* ln_w  = (const float*)d_in[3];
  const float* ln_b  = (const float*)d_in[4];
  const float* W2    = (const float*)d_in[5];
  const float* b2    = (const float*)d_in[6];
  const float* gamma = (const float*)d_in[7];
  float* out = (float*)d_out;

  const int Nr = 8192, DIM = 1024, DFF = 4096, K1 = 3072;

  unsigned short* W1b  = (unsigned short*)d_ws;
  unsigned short* W2b  = W1b + (long)DFF * K1;
  unsigned short* h_in = W2b + (long)DIM * DFF;
  unsigned short* h_act = h_in + (long)Nr * K1;
  float* partial = (float*)(h_act + (long)Nr * DFF);
  float* prefix  = partial + 128 * 1024;
  float* suffix  = prefix + 128 * 1024;

  hipFuncSetAttribute((const void*)gemm256_relu,
                      hipFuncAttributeMaxDynamicSharedMemorySize, 163840);

  cast_bf16<<<2048, 256, 0, stream>>>(W1, W1b, (long)DFF * K1);
  cast_bf16<<<1024, 256, 0, stream>>>(W2, W2b, (long)DIM * DFF);

  scan_chunkmax<<<dim3(4, 128), 256, 0, stream>>>(x, partial);
  scan_chunkscan<<<4, 256, 0, stream>>>(partial, prefix, suffix);
  scan_emit<<<dim3(4, 128), 256, 0, stream>>>(x, prefix, suffix, h_in);

  // GEMM1: h_act = relu(h_in @ W1^T + b1)  — 256^2 pipelined, grid 32x16=512
  gemm256_relu<<<512, 512, 163840, stream>>>(h_in, W1b, h_act, b1, Nr, DFF, K1);

  ln_inplace<<<Nr, 256, 0, stream>>>(h_act, ln_w, ln_b);

  // GEMM2: out = (h_act @ W2^T + b2) * gamma + x  — m97 128^2
  gemm_bt2<<<dim3(DIM / 128, Nr / 128), 256, 0, stream>>>(
      h_act, W2b, out, b2, gamma, x, Nr, DIM, DFF);
}